// Round 5
// baseline (218.762 us; speedup 1.0000x reference)
//
#include <hip/hip_runtime.h>
#include <math.h>

#define NH 512
#define NM 160
#define BROWS 65536
#define BM 128
#define BK 32
#define NCHUNK (NH / BK)   // 16
#define NBLK (BROWS / BM)  // 512

typedef __attribute__((ext_vector_type(8))) __bf16 bf16x8;
typedef __attribute__((ext_vector_type(4))) __bf16 bf16x4;
typedef __attribute__((ext_vector_type(4))) float  f32x4;

// ---------------- kernel 1: M -> bf16, and ||M_j||^2 ----------------
__global__ __launch_bounds__(64) void mprep_kernel(const float* __restrict__ M,
                                                   __bf16* __restrict__ Mb,
                                                   float* __restrict__ mnorm) {
    const int m = blockIdx.x;          // 160 blocks, one wave each
    const int l = threadIdx.x;
    const float* row = M + (size_t)m * NH;
    float s = 0.f;
#pragma unroll
    for (int k = 0; k < 2; ++k) {
        float4 v = *reinterpret_cast<const float4*>(row + 4 * l + 256 * k);
        s = fmaf(v.x, v.x, fmaf(v.y, v.y, fmaf(v.z, v.z, fmaf(v.w, v.w, s))));
        bf16x4 b = {(__bf16)v.x, (__bf16)v.y, (__bf16)v.z, (__bf16)v.w};
        *reinterpret_cast<bf16x4*>(Mb + (size_t)m * NH + 4 * l + 256 * k) = b;
    }
#pragma unroll
    for (int off = 32; off > 0; off >>= 1) s += __shfl_down(s, off);
    if (l == 0) mnorm[m] = s;
}

// ---------------- kernel 2: fused bf16-MFMA GEMM + transform + masked reduce ----
// 256 threads = 4 waves, BK=32 chunks, 3 blocks/CU (12 waves) so cross-block
// overlap hides each block's barrier drain. bf16 LDS rows are 64 B -> fragment
// access is bank-conflict-free with no swizzle. Wave w owns rows [32w,32w+32),
// all 160 motifs as 10 col-tiles of 16; motif class of (ct*16+c) == ct.
__global__ __launch_bounds__(256, 3) void motif_main(
    const float* __restrict__ z, const __bf16* __restrict__ Mb,
    const int* __restrict__ y, const float* __restrict__ mnorm,
    float* __restrict__ loss_sum, unsigned int* __restrict__ done_count,
    float* __restrict__ out) {
    __shared__ __align__(16) __bf16 zs[BM * BK];   // 8 KB
    __shared__ __align__(16) __bf16 ms[NM * BK];   // 10 KB
    __shared__ float znorm[BM];
    __shared__ float red[256];

    const int tid = threadIdx.x;
    const int w   = tid >> 6;          // wave 0..3
    const int l   = tid & 63;
    const int row0 = blockIdx.x * BM;

    f32x4 acc[2][10];
#pragma unroll
    for (int rt = 0; rt < 2; ++rt)
#pragma unroll
        for (int ct = 0; ct < 10; ++ct) acc[rt][ct] = (f32x4){0.f, 0.f, 0.f, 0.f};
    float zp[4] = {0.f, 0.f, 0.f, 0.f};

#pragma unroll 1
    for (int ch = 0; ch < NCHUNK; ++ch) {
        const int k0 = ch * BK;
        // ---- stage z: 128 rows x 8 float4 = 1024, 4/thread; cvt + norm partials
#pragma unroll
        for (int s = 0; s < 4; ++s) {
            const int idx = tid + 256 * s;
            const int r = idx >> 3, c4 = idx & 7;
            float4 v = *reinterpret_cast<const float4*>(
                z + (size_t)(row0 + r) * NH + k0 + c4 * 4);
            zp[s] = fmaf(v.x, v.x, fmaf(v.y, v.y, fmaf(v.z, v.z, fmaf(v.w, v.w, zp[s]))));
            bf16x4 b = {(__bf16)v.x, (__bf16)v.y, (__bf16)v.z, (__bf16)v.w};
            *reinterpret_cast<bf16x4*>(&zs[r * BK + c4 * 4]) = b;
        }
        // ---- stage M: 160 rows x 4 slots(16B) = 640, <=3/thread
#pragma unroll
        for (int s = 0; s < 3; ++s) {
            const int idx = tid + 256 * s;
            if (idx < NM * 4) {
                const int r = idx >> 2, sl = idx & 3;
                bf16x8 v = *reinterpret_cast<const bf16x8*>(
                    Mb + (size_t)r * NH + k0 + sl * 8);
                *reinterpret_cast<bf16x8*>(&ms[r * BK + sl * 8]) = v;
            }
        }
        __syncthreads();

        // ---- compute: 20 MFMA from LDS (conflict-free, no swizzle needed)
        const int r16 = l & 15;
        const int kg  = l >> 4;        // k-group 0..3 (k = kg*8 + e)
        bf16x8 a[2];
#pragma unroll
        for (int rt = 0; rt < 2; ++rt)
            a[rt] = *reinterpret_cast<const bf16x8*>(
                &zs[(w * 32 + rt * 16 + r16) * BK + kg * 8]);
#pragma unroll
        for (int h = 0; h < 2; ++h) {  // ct in halves of 5 to cap VGPR pressure
            bf16x8 b[5];
#pragma unroll
            for (int j = 0; j < 5; ++j)
                b[j] = *reinterpret_cast<const bf16x8*>(
                    &ms[((h * 5 + j) * 16 + r16) * BK + kg * 8]);
#pragma unroll
            for (int rt = 0; rt < 2; ++rt)
#pragma unroll
                for (int j = 0; j < 5; ++j)
                    acc[rt][h * 5 + j] = __builtin_amdgcn_mfma_f32_16x16x32_bf16(
                        a[rt], b[j], acc[rt][h * 5 + j], 0, 0, 0);
        }
        __syncthreads();
    }

    // finish ||z||^2: butterfly over the 8 lanes sharing a row (idx>>3)
#pragma unroll
    for (int s = 0; s < 4; ++s) {
#pragma unroll
        for (int off = 1; off < 8; off <<= 1) zp[s] += __shfl_xor(zp[s], off);
        if ((l & 7) == 0) znorm[(tid + 256 * s) >> 3] = zp[s];
    }
    __syncthreads();

    float mn[10];
#pragma unroll
    for (int ct = 0; ct < 10; ++ct) mn[ct] = mnorm[ct * 16 + (l & 15)];

    // D layout: col = ct*16 + (l&15), row = w*32 + rt*16 + (l>>4)*4 + rr
    float local = 0.f;
#pragma unroll
    for (int rt = 0; rt < 2; ++rt) {
#pragma unroll
        for (int rr = 0; rr < 4; ++rr) {
            const int row = w * 32 + rt * 16 + (l >> 4) * 4 + rr;
            const float nz = znorm[row];
            const int yr = y[row0 + row];
            float p = 0.f, t = 0.f;
#pragma unroll
            for (int ct = 0; ct < 10; ++ct) {
                float dist = nz + mn[ct] - 2.0f * acc[rt][ct][rr];
                float rat = (dist + 1.0f) / (dist + 1e-4f);
                float r2 = rat * rat;
                float sv = r2 * r2 * rat;      // r^5 == exp(log(r)/0.2)
                t += sv;
                p = (ct == yr) ? (p + sv) : p;
            }
#pragma unroll
            for (int off = 1; off < 16; off <<= 1) {
                p += __shfl_xor(p, off);
                t += __shfl_xor(t, off);
            }
            if ((l & 15) == 0) local += logf(p / t);
        }
    }

    red[tid] = local;
    __syncthreads();
#pragma unroll 1
    for (int s = 128; s > 0; s >>= 1) {
        if (tid < s) red[tid] += red[tid + s];
        __syncthreads();
    }
    if (tid == 0) {
        atomicAdd(loss_sum, red[0]);
        __threadfence();                                  // release our add
        unsigned prev = atomicAdd(done_count, 1u);
        if (prev == (unsigned)(NBLK - 1)) {               // last block finalizes
            __threadfence();                              // acquire
            float total = atomicAdd(loss_sum, 0.0f);      // device-scope read
            out[0] = -total * (1.0f / (float)BROWS);
        }
    }
}

extern "C" void kernel_launch(void* const* d_in, const int* in_sizes, int n_in,
                              void* d_out, int out_size, void* d_ws, size_t ws_size,
                              hipStream_t stream) {
    const float* z = (const float*)d_in[0];
    const float* M = (const float*)d_in[1];
    const int*   y = (const int*)d_in[2];
    float* out = (float*)d_out;

    // workspace: [0,160KB) M bf16; mnorm[160] f32; loss_sum f32; done_count u32
    __bf16* Mb       = (__bf16*)d_ws;
    float*  mnorm    = (float*)((char*)d_ws + (size_t)NM * NH * sizeof(__bf16));
    float*  loss_sum = mnorm + NM;
    unsigned int* done_count = (unsigned int*)(loss_sum + 1);

    hipMemsetAsync(loss_sum, 0, 2 * sizeof(float), stream);  // zero sum + counter
    mprep_kernel<<<NM, 64, 0, stream>>>(M, Mb, mnorm);
    motif_main<<<NBLK, 256, 0, stream>>>(z, Mb, y, mnorm, loss_sum, done_count, out);
}